// Round 6
// baseline (269.505 us; speedup 1.0000x reference)
//
#include <hip/hip_runtime.h>
#include <math.h>

#define BB 4
#define LQ 8400
#define NH 8
#define LVTOT 8500
#define HD 32
#define NQB 525      // queries per sampler block (16 chunks x 525 = 8400)

typedef __attribute__((ext_vector_type(8))) short short8;
typedef __attribute__((ext_vector_type(4))) float f32x4;
typedef __attribute__((ext_vector_type(2))) float f32x2;
typedef __attribute__((ext_vector_type(2))) _Float16 half2_t;
typedef __attribute__((ext_vector_type(2))) __fp16 fp16x2_t;
typedef unsigned short ushort_t;

__device__ __forceinline__ ushort_t f2bf(float f) {
    union { float f; unsigned u; } v; v.f = f;
    unsigned r = v.u + 0x7fffu + ((v.u >> 16) & 1u);   // RNE
    return (ushort_t)(r >> 16);
}
__device__ __forceinline__ float bflo(unsigned u) {
    union { unsigned u; float f; } x; x.u = u << 16; return x.f;
}
__device__ __forceinline__ float bfhi(unsigned u) {
    union { unsigned u; float f; } x; x.u = u & 0xffff0000u; return x.f;
}
__device__ __forceinline__ half2_t ash2(unsigned u) {
    union { unsigned u; half2_t h; } x; x.u = u; return x.h;
}
__device__ __forceinline__ unsigned pk2u(fp16x2_t h) {
    union { fp16x2_t h; unsigned u; } x; x.h = h; return x.u;
}

// async global->LDS DMA, 16 B per lane (wave-uniform LDS base + lane*16)
__device__ __forceinline__ void dma16(const ushort_t* g, ushort_t* l) {
    __builtin_amdgcn_global_load_lds(
        (const __attribute__((address_space(1))) void*)g,
        (__attribute__((address_space(3))) void*)l, 16, 0, 0);
}

// ---------------------------------------------------------------------------
// Merged prep: blocks [0,8500) cast value, [8500,16900) cast query,
// [16900,17796) build BT (transposed bf16 weights, 896 rows x 256 k).
// ---------------------------------------------------------------------------
__global__ __launch_bounds__(256) void prep_all(
    const float* __restrict__ value, const float* __restrict__ query,
    const float* __restrict__ Wv, const float* __restrict__ Woff,
    const float* __restrict__ Wattn, const float* __restrict__ Wo,
    ushort_t* __restrict__ value_b, ushort_t* __restrict__ query_b,
    ushort_t* __restrict__ BT)
{
    const int bid = blockIdx.x;
    if (bid < 16900) {
        const float* src = (bid < 8500) ? value : query;
        ushort_t* dst = (bid < 8500) ? value_b : query_b;
        int i = (bid < 8500 ? bid : bid - 8500) * 256 + threadIdx.x;
        float4 f = ((const float4*)src)[i];
        ushort4 o;
        o.x = f2bf(f.x); o.y = f2bf(f.y); o.z = f2bf(f.z); o.w = f2bf(f.w);
        ((ushort4*)dst)[i] = o;
    } else {
        int idx = (bid - 16900) * 256 + threadIdx.x;   // 896*256
        int r = idx >> 8, k = idx & 255;
        float v;
        if (r < 256) v = Wv[k * 256 + r];
        else if (r < 640) {
            int n = r - 256;
            v = (n < 256) ? Woff[k * 256 + n] : Wattn[k * 128 + (n - 256)];
        } else v = Wo[k * 256 + (r - 640)];
        BT[idx] = f2bf(v);
    }
}

// ---------------------------------------------------------------------------
// GEMM core v2: 128x128 tile, 4 waves, BK=64, K=256 (4 steps), DOUBLE-
// buffered LDS + T3-minimum 2-phase pipeline: issue STAGE(t+1), counted
// s_waitcnt vmcnt(8) (previous stage landed, next stays in flight), raw
// s_barrier, compute(t). Hides stage latency under MFMA instead of the
// serial stage->drain->compute of the old core. LDS 64 KB -> 2 blocks/CU.
// ---------------------------------------------------------------------------
__device__ __forceinline__ void gemm_core(
    const ushort_t* __restrict__ A, const ushort_t* __restrict__ B, int M,
    int m0, int n0, ushort_t* Asl, ushort_t* Bsl, f32x4 acc[4][4])
{
    const int tid  = threadIdx.x;
    const int wave = tid >> 6, lane = tid & 63;
    const int quad = lane >> 4, mr = lane & 15;
    const int wm   = (wave >> 1) * 64, wn = (wave & 1) * 64;
    const int oct  = lane >> 3;       // 0..7 row-in-wave-slab
    const int bseg = lane & 7;        // physical 16B slot within row

    auto STAGE = [&](int s, int buf) {
        const int k0 = s * 64;
        ushort_t* Ad = Asl + buf * (128 * 64);
        ushort_t* Bd = Bsl + buf * (128 * 64);
        #pragma unroll
        for (int i = 0; i < 4; i++) {
            int m  = i * 32 + wave * 8 + oct;          // block-relative row
            int gs = bseg ^ (m & 7);                   // swizzled source seg
            int am = min(m0 + m, M - 1);
            dma16(A + (size_t)am * 256 + k0 + gs * 8,
                  Ad + (i * 32 + wave * 8) * 64 + lane * 8);
            int bn = n0 + m;
            dma16(B + (size_t)bn * 256 + k0 + gs * 8,
                  Bd + (i * 32 + wave * 8) * 64 + lane * 8);
        }
    };

    STAGE(0, 0);                      // prologue
    #pragma unroll
    for (int t = 0; t < 4; t++) {
        if (t < 3) {
            STAGE(t + 1, (t + 1) & 1);
            // previous stage (8 dma) landed; next stage's 8 stay in flight
            asm volatile("s_waitcnt vmcnt(8)" ::: "memory");
        } else {
            asm volatile("s_waitcnt vmcnt(0)" ::: "memory");
        }
        __builtin_amdgcn_s_barrier();
        __builtin_amdgcn_sched_barrier(0);

        const ushort_t* As = Asl + (t & 1) * (128 * 64);
        const ushort_t* Bs = Bsl + (t & 1) * (128 * 64);
        #pragma unroll
        for (int ks = 0; ks < 2; ks++) {
            short8 af[4], bf[4];
            const int ksl = ks * 4 + quad;
            #pragma unroll
            for (int i = 0; i < 4; i++) {
                int m = wm + i * 16 + mr;
                af[i] = *(const short8*)&As[m * 64 + (ksl ^ (m & 7)) * 8];
                int n = wn + i * 16 + mr;
                bf[i] = *(const short8*)&Bs[n * 64 + (ksl ^ (n & 7)) * 8];
            }
            #pragma unroll
            for (int i = 0; i < 4; i++)
                #pragma unroll
                for (int j = 0; j < 4; j++)
                    acc[i][j] = __builtin_amdgcn_mfma_f32_16x16x32_bf16(
                        af[i], bf[j], acc[i][j], 0, 0, 0);
        }
        __builtin_amdgcn_sched_barrier(0);
        __builtin_amdgcn_s_barrier();  // readers done before buf reuse at t+2
    }
}

// ---------------------------------------------------------------------------
// Fused GEMM1 (value->vperm f16, 532 blocks) + GEMM2 (query->off/awl, 789).
// ---------------------------------------------------------------------------
__global__ __launch_bounds__(256, 2) void gemm_fused(
    const ushort_t* __restrict__ Av, const ushort_t* __restrict__ Aq,
    const ushort_t* __restrict__ BT,
    const float* __restrict__ bv, const float* __restrict__ boff,
    const float* __restrict__ battn,
    ushort_t* __restrict__ vperm, ushort_t* __restrict__ off_b,
    ushort_t* __restrict__ awl_b)
{
    __shared__ ushort_t Asl[2 * 128 * 64];
    __shared__ ushort_t Bsl[2 * 128 * 64];

    const int bid = blockIdx.x;
    int mode, m0, n0, M;
    const ushort_t *A, *B;
    if (bid < 532) { mode = 0; m0 = (bid >> 1) * 128; n0 = (bid & 1) * 128;
                     A = Av; B = BT; M = 34000; }
    else { int b2 = bid - 532;
           mode = 1; m0 = (b2 / 3) * 128; n0 = (b2 % 3) * 128;
           A = Aq; B = BT + 65536; M = 33600; }

    f32x4 acc[4][4];
    #pragma unroll
    for (int i = 0; i < 4; i++)
        #pragma unroll
        for (int j = 0; j < 4; j++) acc[i][j] = (f32x4){0.f, 0.f, 0.f, 0.f};

    gemm_core(A, B, M, m0, n0, Asl, Bsl, acc);

    const int tid  = threadIdx.x;
    const int wave = tid >> 6, lane = tid & 63;
    const int quad = lane >> 4, mr = lane & 15;
    const int wm   = (wave >> 1) * 64, wn = (wave & 1) * 64;

    #pragma unroll
    for (int i = 0; i < 4; i++) {
        const int rbase = m0 + wm + i * 16 + quad * 4;
        #pragma unroll
        for (int j = 0; j < 4; j++) {
            const int c = n0 + wn + j * 16 + mr;
            #pragma unroll
            for (int reg = 0; reg < 4; reg++) {
                int row = rbase + reg;
                if (row >= M) continue;
                float val = acc[i][j][reg];
                if (mode == 0) {
                    float o = val + bv[c];
                    int b = row / LVTOT, pix = row - b * LVTOT;
                    int h = c >> 5, d = c & 31;
                    union { _Float16 h16; ushort_t u; } cv;
                    cv.h16 = (_Float16)o;                       // f16 plane
                    vperm[(((size_t)(b * NH + h)) * LVTOT + pix) * HD + d] = cv.u;
                } else {
                    if (c < 256) off_b[(size_t)row * 256 + c] = f2bf(val + boff[c]);
                    else awl_b[(size_t)row * 128 + (c - 256)] = f2bf(val + battn[c - 256]);
                }
            }
        }
    }
}

// ---------------------------------------------------------------------------
// GEMM3: sampled(bf16) @ Wo + bo -> out fp32
// ---------------------------------------------------------------------------
__global__ __launch_bounds__(256, 2) void gemm_out(
    const ushort_t* __restrict__ A, const ushort_t* __restrict__ BT,
    const float* __restrict__ bo, float* __restrict__ out)
{
    __shared__ ushort_t Asl[2 * 128 * 64];
    __shared__ ushort_t Bsl[2 * 128 * 64];

    const int m0 = (blockIdx.x >> 1) * 128;    // adjacency swizzle (263x2)
    const int n0 = (blockIdx.x & 1) * 128;
    const int M = 33600;

    f32x4 acc[4][4];
    #pragma unroll
    for (int i = 0; i < 4; i++)
        #pragma unroll
        for (int j = 0; j < 4; j++) acc[i][j] = (f32x4){0.f, 0.f, 0.f, 0.f};

    gemm_core(A, BT, M, m0, n0, Asl, Bsl, acc);

    const int tid  = threadIdx.x;
    const int wave = tid >> 6, lane = tid & 63;
    const int quad = lane >> 4, mr = lane & 15;
    const int wm   = (wave >> 1) * 64, wn = (wave & 1) * 64;

    #pragma unroll
    for (int i = 0; i < 4; i++) {
        const int rbase = m0 + wm + i * 16 + quad * 4;
        #pragma unroll
        for (int j = 0; j < 4; j++) {
            const int c = n0 + wn + j * 16 + mr;
            #pragma unroll
            for (int reg = 0; reg < 4; reg++) {
                int row = rbase + reg;
                if (row >= M) continue;
                out[(size_t)row * 256 + c] = acc[i][j][reg] + bo[c];
            }
        }
    }
}

// ---------------------------------------------------------------------------
// Sampler v9 (unchanged from round 5): per-(b,h) mega-blocks, LDS-staged
// l1+l2, 16 lanes/query (4 global pts + 4 LDS pts per 8-lane half).
// ---------------------------------------------------------------------------
__global__ __launch_bounds__(1024) void msda_sample(
    const ushort_t* __restrict__ vperm, const ushort_t* __restrict__ off,
    const ushort_t* __restrict__ awl, const float* __restrict__ refp,
    ushort_t* __restrict__ sampled)
{
    __shared__ ushort_t lds_v[2000 * HD];      // 128,000 B: l1 (0..1599), l2 (1600..1999)
    __shared__ uint2    s_w[64 * 17];          // (w00,w01)|(w10,w11) f16x2, stride 17
    __shared__ ushort4  s_iv[64 * 17];         // corner pixel indices

    const int tid   = threadIdx.x;
    const int bid   = blockIdx.x;
    const int h     = bid & 7;                 // XCD-pinned head
    const int b     = (bid >> 3) & 3;
    const int chunk = bid >> 5;                // 0..15
    const int q0    = chunk * NQB;             // first query in batch b
    const size_t bq0 = (size_t)b * LQ + q0;

    const ushort_t* plane = vperm + (size_t)(b * NH + h) * (LVTOT * HD);

    // ---- stage l1+l2 (pixels 6400..8399) into LDS: 8000 x 16 B ----
    {
        const ushort_t* psrc = plane + 6400 * HD;
        #pragma unroll
        for (int it = 0; it < 8; it++) {
            int i = it * 1024 + tid;
            if (i < 8000) dma16(psrc + i * 8, lds_v + i * 8);
        }
    }

    const int Hs[4]    = {80, 40, 20, 10};
    const int base2[4] = {0, 0, 1600, 8400};   // l0 raw, l1/l2 LDS-rebased, l3 raw

    const int NPASS = (NQB + 63) / 64;         // 9

    // ---------------- phase 1 for pass 0 ----------------
    {
        const int ql = tid >> 4, lp = tid & 15;
        const int l  = lp >> 2;
        const int lq = min(ql, NQB - 1);       // pass 0: q index = ql
        const size_t bq = bq0 + lq;
        const int Wl = Hs[l];

        unsigned od = *(const unsigned*)(off + bq * 256 + h * 32 + lp * 2);
        float ox = bflo(od), oy = bfhi(od);
        float lgt = bflo((unsigned)awl[bq * 128 + h * 16 + lp]);
        float e = __expf(lgt);
        float sum = e;
        sum += __shfl_xor(sum, 1, 16);
        sum += __shfl_xor(sum, 2, 16);
        sum += __shfl_xor(sum, 4, 16);
        sum += __shfl_xor(sum, 8, 16);
        float aw = e * __builtin_amdgcn_rcpf(sum);

        float2 rp = *(const float2*)(refp + bq * 8 + l * 2);
        float x = rp.x * (float)Wl + ox - 0.5f;
        float y = rp.y * (float)Wl + oy - 0.5f;
        float x0f = floorf(x), y0f = floorf(y);
        float wx = x - x0f, wy = y - y0f;
        int x0 = (int)x0f, y0 = (int)y0f;
        bool vx0 = (x0 >= 0) & (x0 < Wl);
        bool vx1 = (x0 + 1 >= 0) & (x0 + 1 < Wl);
        bool vy0 = (y0 >= 0) & (y0 < Wl);
        bool vy1 = (y0 + 1 >= 0) & (y0 + 1 < Wl);
        int cx0 = min(max(x0, 0), Wl - 1);
        int cx1 = min(max(x0 + 1, 0), Wl - 1);
        int cy0 = min(max(y0, 0), Wl - 1);
        int cy1 = min(max(y0 + 1, 0), Wl - 1);
        float w00 = (vx0 && vy0) ? (1.f - wx) * (1.f - wy) * aw : 0.f;
        float w01 = (vx1 && vy0) ? wx * (1.f - wy) * aw : 0.f;
        float w10 = (vx0 && vy1) ? (1.f - wx) * wy * aw : 0.f;
        float w11 = (vx1 && vy1) ? wx * wy * aw : 0.f;
        const int rec = ql * 17 + lp;
        const int bs = base2[l];
        s_w[rec] = make_uint2(pk2u(__builtin_amdgcn_cvt_pkrtz(w00, w01)),
                              pk2u(__builtin_amdgcn_cvt_pkrtz(w10, w11)));
        s_iv[rec] = make_ushort4((ushort_t)(bs + cy0 * Wl + cx0),
                                 (ushort_t)(bs + cy0 * Wl + cx1),
                                 (ushort_t)(bs + cy1 * Wl + cx0),
                                 (ushort_t)(bs + cy1 * Wl + cx1));
    }
    __syncthreads();   // staging landed + s_w/s_iv visible

    for (int p = 0; ; p++) {
        // ---------------- phase 2: pass p ----------------
        {
            const int ql  = tid >> 4;          // 0..63
            const int sub = tid & 15;
            const int g   = sub >> 3;          // 0: pts {0-3 glob,4-7 lds}; 1: {12-15 glob,8-11 lds}
            const int dsh = (sub & 7) * 4;     // ushort element offset of this lane's 4 dims
            const int dby = (sub & 7) * 8;     // byte offset
            const int lq  = p * 64 + ql;

            float a0 = 0.f, a1 = 0.f, a2 = 0.f, a3 = 0.f;

            // issue 4 global pts (l0 for g0, l3 for g1)
            uint2 gw[4]; ushort4 giv[4];
            uint2 gv0[4], gv1[4], gv2[4], gv3[4];
            #pragma unroll
            for (int pi = 0; pi < 4; pi++) {
                const int pt = g ? (12 + pi) : pi;
                const int rec = ql * 17 + pt;
                gw[pi]  = s_w[rec];
                giv[pi] = s_iv[rec];
                gv0[pi] = *(const uint2*)((const char*)plane + (((unsigned)giv[pi].x << 6) + dby));
                gv1[pi] = *(const uint2*)((const char*)plane + (((unsigned)giv[pi].y << 6) + dby));
                gv2[pi] = *(const uint2*)((const char*)plane + (((unsigned)giv[pi].z << 6) + dby));
                gv3[pi] = *(const uint2*)((const char*)plane + (((unsigned)giv[pi].w << 6) + dby));
            }
            // 4 LDS pts (l1 for g0, l2 for g1) — hides global latency
            #pragma unroll
            for (int pi = 0; pi < 4; pi++) {
                const int pt = g ? (8 + pi) : (4 + pi);
                const int rec = ql * 17 + pt;
                uint2 w = s_w[rec];
                ushort4 iv = s_iv[rec];
                uint2 v0 = *(const uint2*)&lds_v[(unsigned)iv.x * HD + dsh];
                uint2 v1 = *(const uint2*)&lds_v[(unsigned)iv.y * HD + dsh];
                uint2 v2 = *(const uint2*)&lds_v[(unsigned)iv.z * HD + dsh];
                uint2 v3 = *(const uint2*)&lds_v[(unsigned)iv.w * HD + dsh];
                half2_t w01 = ash2(w.x), w23 = ash2(w.y);
                unsigned p01lo = __builtin_amdgcn_perm(v1.x, v0.x, 0x05040100);
                unsigned p01hi = __builtin_amdgcn_perm(v1.x, v0.x, 0x07060302);
                unsigned p23lo = __builtin_amdgcn_perm(v3.x, v2.x, 0x05040100);
                unsigned p23hi = __builtin_amdgcn_perm(v3.x, v2.x, 0x07060302);
                a0 = __builtin_amdgcn_fdot2(w01, ash2(p01lo), a0, false);
                a0 = __builtin_amdgcn_fdot2(w23, ash2(p23lo), a0, false);
                a1 = __builtin_amdgcn_fdot2(w01, ash2(p01hi), a1, false);
                a1 = __builtin_amdgcn_fdot2(w23, ash2(p23hi), a1, false);
                unsigned q01lo = __builtin_amdgcn_perm(v1.y, v0.y, 0x05040100);
                unsigned q01hi = __builtin_amdgcn_perm(v1.y, v0.y, 0x07060302);
                unsigned q23lo = __builtin_amdgcn_perm(v3.y, v2.y, 0x05040100);
                unsigned q23hi = __builtin_amdgcn_perm(v3.y, v2.y, 0x07060302);
                a2 = __builtin_amdgcn_fdot2(w01, ash2(q01lo), a2, false);
                a2 = __builtin_amdgcn_fdot2(w23, ash2(q23lo), a2, false);
                a3 = __builtin_amdgcn_fdot2(w01, ash2(q01hi), a3, false);
                a3 = __builtin_amdgcn_fdot2(w23, ash2(q23hi), a3, false);
            }
            // consume globals
            #pragma unroll
            for (int pi = 0; pi < 4; pi++) {
                half2_t w01 = ash2(gw[pi].x), w23 = ash2(gw[pi].y);
                unsigned p01lo = __builtin_amdgcn_perm(gv1[pi].x, gv0[pi].x, 0x05040100);
                unsigned p01hi = __builtin_amdgcn_perm(gv1[pi].x, gv0[pi].x, 0x07060302);
                unsigned p23lo = __builtin_amdgcn_perm(gv3[pi].x, gv2[pi].x, 0x05040100);
                unsigned p23hi = __builtin_amdgcn_perm(gv3[pi].x, gv2[pi].x, 0x07060302);
                a0 = __builtin_amdgcn_fdot2(w01, ash2(p01lo), a0, false);
                a0 = __builtin_amdgcn_fdot2(w23, ash2(p23lo), a0, false);
                a1 = __builtin_amdgcn_fdot2(w01, ash2(p01hi), a1, false);
                a1 = __builtin_amdgcn_fdot2(w23, ash2(p23hi), a1, false);
                unsigned q01lo = __builtin_amdgcn_perm(gv1[pi].y, gv0[pi].y, 0x05040100);
                unsigned q01hi = __builtin_amdgcn_perm(gv1[pi].y, gv0[pi].y, 0x07060302);
                unsigned q23lo = __builtin_amdgcn_perm(gv3[pi].y, gv2[pi].y, 0x05040100);
                unsigned q23hi = __builtin_amdgcn_perm(gv3[pi].y, gv2[pi].y, 0x07060302);
                a2 = __builtin_amdgcn_fdot2(w01, ash2(q01lo), a2, false);
                a2 = __builtin_amdgcn_fdot2(w23, ash2(q23lo), a2, false);
                a3 = __builtin_amdgcn_fdot2(w01, ash2(q01hi), a3, false);
                a3 = __builtin_amdgcn_fdot2(w23, ash2(q23hi), a3, false);
            }
            // combine the two 8-lane halves (sub ^ 8)
            a0 += __shfl_xor(a0, 8);
            a1 += __shfl_xor(a1, 8);
            a2 += __shfl_xor(a2, 8);
            a3 += __shfl_xor(a3, 8);
            if (sub < 8 && lq < NQB) {
                const size_t bq = bq0 + lq;
                ushort4 o;
                o.x = f2bf(a0); o.y = f2bf(a1);
                o.z = f2bf(a2); o.w = f2bf(a3);
                *(ushort4*)(sampled + bq * 256 + h * 32 + dsh) = o;
            }
        }
        if (p + 1 >= NPASS) break;
        __syncthreads();   // phase2 readers done before s_w overwrite

        // ---------------- phase 1 for pass p+1 ----------------
        {
            const int ql = tid >> 4, lp = tid & 15;
            const int l  = lp >> 2;
            const int lq = min((p + 1) * 64 + ql, NQB - 1);
            const size_t bq = bq0 + lq;
            const int Wl = Hs[l];

            unsigned od = *(const unsigned*)(off + bq * 256 + h * 32 + lp * 2);
            float ox = bflo(od), oy = bfhi(od);
            float lgt = bflo((unsigned)awl[bq * 128 + h * 16 + lp]);
            float e = __expf(lgt);
            float sum = e;
            sum += __shfl_xor(sum, 1, 16);
            sum += __shfl_xor(sum, 2, 16);
            sum += __shfl_xor(sum, 4, 16);
            sum += __shfl_xor(sum, 8, 16);
            float aw = e * __builtin_amdgcn_rcpf(sum);

            float2 rp = *(const float2*)(refp + bq * 8 + l * 2);
            float x = rp.x * (float)Wl + ox - 0.5f;
            float y = rp.y * (float)Wl + oy - 0.5f;
            float x0f = floorf(x), y0f = floorf(y);
            float wx = x - x0f, wy = y - y0f;
            int x0 = (int)x0f, y0 = (int)y0f;
            bool vx0 = (x0 >= 0) & (x0 < Wl);
            bool vx1 = (x0 + 1 >= 0) & (x0 + 1 < Wl);
            bool vy0 = (y0 >= 0) & (y0 < Wl);
            bool vy1 = (y0 + 1 >= 0) & (y0 + 1 < Wl);
            int cx0 = min(max(x0, 0), Wl - 1);
            int cx1 = min(max(x0 + 1, 0), Wl - 1);
            int cy0 = min(max(y0, 0), Wl - 1);
            int cy1 = min(max(y0 + 1, 0), Wl - 1);
            float w00 = (vx0 && vy0) ? (1.f - wx) * (1.f - wy) * aw : 0.f;
            float w01 = (vx1 && vy0) ? wx * (1.f - wy) * aw : 0.f;
            float w10 = (vx0 && vy1) ? (1.f - wx) * wy * aw : 0.f;
            float w11 = (vx1 && vy1) ? wx * wy * aw : 0.f;
            const int rec = ql * 17 + lp;
            const int bs = base2[l];
            s_w[rec] = make_uint2(pk2u(__builtin_amdgcn_cvt_pkrtz(w00, w01)),
                                  pk2u(__builtin_amdgcn_cvt_pkrtz(w10, w11)));
            s_iv[rec] = make_ushort4((ushort_t)(bs + cy0 * Wl + cx0),
                                     (ushort_t)(bs + cy0 * Wl + cx1),
                                     (ushort_t)(bs + cy1 * Wl + cx0),
                                     (ushort_t)(bs + cy1 * Wl + cx1));
        }
        __syncthreads();   // s_w/s_iv for pass p+1 visible
    }
}

extern "C" void kernel_launch(void* const* d_in, const int* in_sizes, int n_in,
                              void* d_out, int out_size, void* d_ws, size_t ws_size,
                              hipStream_t stream) {
    const float* query = (const float*)d_in[0];
    const float* refp  = (const float*)d_in[1];
    const float* value = (const float*)d_in[2];
    const float* Wv    = (const float*)d_in[4];
    const float* bv    = (const float*)d_in[5];
    const float* Woff  = (const float*)d_in[6];
    const float* boff  = (const float*)d_in[7];
    const float* Wattn = (const float*)d_in[8];
    const float* battn = (const float*)d_in[9];
    const float* Wo    = (const float*)d_in[10];
    const float* bo    = (const float*)d_in[11];
    float* out = (float*)d_out;

    ushort_t* ws = (ushort_t*)d_ws;
    ushort_t* off_b   = ws;                       // 33600*256
    ushort_t* awl_b   = off_b + 8601600;          // 33600*128
    ushort_t* value_b = awl_b + 4300800;          // 34000*256
    ushort_t* query_b = value_b + 8704000;        // 33600*256 (aliased w/ sampled)
    ushort_t* vperm_b = query_b + 8601600;        // 34000*256 (f16)
    ushort_t* BT      = vperm_b + 8704000;        // 896*256
    ushort_t* sampled_b = query_b;                // alias: query dead after gemm_fused

    prep_all<<<dim3(17796), 256, 0, stream>>>(
        value, query, Wv, Woff, Wattn, Wo, value_b, query_b, BT);

    gemm_fused<<<dim3(532 + 789), 256, 0, stream>>>(
        value_b, query_b, BT, bv, boff, battn, vperm_b, off_b, awl_b);

    msda_sample<<<dim3(512), 1024, 0, stream>>>(
        vperm_b, off_b, awl_b, refp, sampled_b);

    gemm_out<<<dim3(526), 256, 0, stream>>>(
        sampled_b, BT + 163840, bo, out);
}

// Round 7
// 228.027 us; speedup vs baseline: 1.1819x; 1.1819x over previous
//
#include <hip/hip_runtime.h>
#include <math.h>

#define BB 4
#define LQ 8400
#define NH 8
#define LVTOT 8500
#define HD 32
#define PLANE_USH 544000   // 8500 pairs x 64 ushorts (2 parity copies of 4250)

typedef __attribute__((ext_vector_type(8))) short short8;
typedef __attribute__((ext_vector_type(4))) float f32x4;
typedef __attribute__((ext_vector_type(2))) _Float16 half2_t;
typedef __attribute__((ext_vector_type(2))) __fp16 fp16x2_t;
typedef unsigned short ushort_t;

__device__ __forceinline__ ushort_t f2bf(float f) {
    union { float f; unsigned u; } v; v.f = f;
    unsigned r = v.u + 0x7fffu + ((v.u >> 16) & 1u);   // RNE
    return (ushort_t)(r >> 16);
}
__device__ __forceinline__ float bflo(unsigned u) {
    union { unsigned u; float f; } x; x.u = u << 16; return x.f;
}
__device__ __forceinline__ float bfhi(unsigned u) {
    union { unsigned u; float f; } x; x.u = u & 0xffff0000u; return x.f;
}
__device__ __forceinline__ half2_t ash2(unsigned u) {
    union { unsigned u; half2_t h; } x; x.u = u; return x.h;
}
__device__ __forceinline__ unsigned pk2u(fp16x2_t h) {
    union { fp16x2_t h; unsigned u; } x; x.h = h; return x.u;
}

// async global->LDS DMA, 16 B per lane (wave-uniform LDS base + lane*16)
__device__ __forceinline__ void dma16(const ushort_t* g, ushort_t* l) {
    __builtin_amdgcn_global_load_lds(
        (const __attribute__((address_space(1))) void*)g,
        (__attribute__((address_space(3))) void*)l, 16, 0, 0);
}

// ---------------------------------------------------------------------------
// Merged prep: blocks [0,8500) cast value, [8500,16900) cast query,
// [16900,17796) build BT (transposed bf16 weights, 896 rows x 256 k).
// ---------------------------------------------------------------------------
__global__ __launch_bounds__(256) void prep_all(
    const float* __restrict__ value, const float* __restrict__ query,
    const float* __restrict__ Wv, const float* __restrict__ Woff,
    const float* __restrict__ Wattn, const float* __restrict__ Wo,
    ushort_t* __restrict__ value_b, ushort_t* __restrict__ query_b,
    ushort_t* __restrict__ BT)
{
    const int bid = blockIdx.x;
    if (bid < 16900) {
        const float* src = (bid < 8500) ? value : query;
        ushort_t* dst = (bid < 8500) ? value_b : query_b;
        int i = (bid < 8500 ? bid : bid - 8500) * 256 + threadIdx.x;
        float4 f = ((const float4*)src)[i];
        ushort4 o;
        o.x = f2bf(f.x); o.y = f2bf(f.y); o.z = f2bf(f.z); o.w = f2bf(f.w);
        ((ushort4*)dst)[i] = o;
    } else {
        int idx = (bid - 16900) * 256 + threadIdx.x;   // 896*256
        int r = idx >> 8, k = idx & 255;
        float v;
        if (r < 256) v = Wv[k * 256 + r];
        else if (r < 640) {
            int n = r - 256;
            v = (n < 256) ? Woff[k * 256 + n] : Wattn[k * 128 + (n - 256)];
        } else v = Wo[k * 256 + (r - 640)];
        BT[idx] = f2bf(v);
    }
}

// ---------------------------------------------------------------------------
// Shared GEMM core (round-5 serial, proven): 128x128 tile, 4 waves, BK=64.
// Staging via global_load_lds dwordx4; XOR swizzle on the GLOBAL segment.
// ---------------------------------------------------------------------------
__device__ __forceinline__ void gemm_core(
    const ushort_t* __restrict__ A, const ushort_t* __restrict__ B, int M,
    int m0, int n0, ushort_t* Asl, ushort_t* Bsl, f32x4 acc[4][4])
{
    const int tid  = threadIdx.x;
    const int wave = tid >> 6, lane = tid & 63;
    const int quad = lane >> 4, mr = lane & 15;
    const int wm   = (wave >> 1) * 64, wn = (wave & 1) * 64;
    const int oct  = lane >> 3;       // 0..7 row-in-wave-slab
    const int bseg = lane & 7;        // physical 16B slot within row

    for (int k0 = 0; k0 < 256; k0 += 64) {
        __syncthreads();              // prior iteration's reads done
        #pragma unroll
        for (int i = 0; i < 4; i++) {
            int m  = i * 32 + wave * 8 + oct;          // block-relative row
            int gs = bseg ^ (m & 7);                   // swizzled source seg
            int am = min(m0 + m, M - 1);
            dma16(A + (size_t)am * 256 + k0 + gs * 8,
                  Asl + (size_t)(i * 32 + wave * 8) * 64 + lane * 8);
            int bn = n0 + m;
            dma16(B + (size_t)bn * 256 + k0 + gs * 8,
                  Bsl + (size_t)(i * 32 + wave * 8) * 64 + lane * 8);
        }
        __syncthreads();              // DMA landed
        #pragma unroll
        for (int ks = 0; ks < 2; ks++) {
            short8 af[4], bf[4];
            const int ksl = ks * 4 + quad;
            #pragma unroll
            for (int i = 0; i < 4; i++) {
                int m = wm + i * 16 + mr;
                af[i] = *(const short8*)&Asl[m * 64 + (ksl ^ (m & 7)) * 8];
                int n = wn + i * 16 + mr;
                bf[i] = *(const short8*)&Bsl[n * 64 + (ksl ^ (n & 7)) * 8];
            }
            #pragma unroll
            for (int i = 0; i < 4; i++)
                #pragma unroll
                for (int j = 0; j < 4; j++)
                    acc[i][j] = __builtin_amdgcn_mfma_f32_16x16x32_bf16(
                        af[i], bf[j], acc[i][j], 0, 0, 0);
        }
    }
}

// ---------------------------------------------------------------------------
// Fused GEMM1 (value->vperm f16 PAIR-INTERLEAVED x2 parity copies) +
// GEMM2 (query->off/awl). Adjacency swizzle on bids.
// Pair layout per (b,h) plane: copy c in {0,1}, level pair-bases
// {0,3200,4000,4200} (of 4250), pair idx = y*(W/2)+p, word [pair][d][2].
// ---------------------------------------------------------------------------
__global__ __launch_bounds__(256, 3) void gemm_fused(
    const ushort_t* __restrict__ Av, const ushort_t* __restrict__ Aq,
    const ushort_t* __restrict__ BT,
    const float* __restrict__ bv, const float* __restrict__ boff,
    const float* __restrict__ battn,
    ushort_t* __restrict__ vperm, ushort_t* __restrict__ off_b,
    ushort_t* __restrict__ awl_b)
{
    __shared__ ushort_t Asl[128 * 64];
    __shared__ ushort_t Bsl[128 * 64];

    const int bid = blockIdx.x;
    int mode, m0, n0, M;
    const ushort_t *A, *B;
    if (bid < 532) { mode = 0; m0 = (bid >> 1) * 128; n0 = (bid & 1) * 128;
                     A = Av; B = BT; M = 34000; }
    else { int b2 = bid - 532;
           mode = 1; m0 = (b2 / 3) * 128; n0 = (b2 % 3) * 128;
           A = Aq; B = BT + 65536; M = 33600; }

    f32x4 acc[4][4];
    #pragma unroll
    for (int i = 0; i < 4; i++)
        #pragma unroll
        for (int j = 0; j < 4; j++) acc[i][j] = (f32x4){0.f, 0.f, 0.f, 0.f};

    gemm_core(A, B, M, m0, n0, Asl, Bsl, acc);

    const int tid  = threadIdx.x;
    const int wave = tid >> 6, lane = tid & 63;
    const int quad = lane >> 4, mr = lane & 15;
    const int wm   = (wave >> 1) * 64, wn = (wave & 1) * 64;

    #pragma unroll
    for (int i = 0; i < 4; i++) {
        const int rbase = m0 + wm + i * 16 + quad * 4;
        #pragma unroll
        for (int j = 0; j < 4; j++) {
            const int c = n0 + wn + j * 16 + mr;
            #pragma unroll
            for (int reg = 0; reg < 4; reg++) {
                int row = rbase + reg;
                if (row >= M) continue;
                float val = acc[i][j][reg];
                if (mode == 0) {
                    float o = val + bv[c];
                    int b = row / LVTOT, pix = row - b * LVTOT;
                    int h = c >> 5, d = c & 31;
                    union { _Float16 h16; ushort_t u; } cv;
                    cv.h16 = (_Float16)o;
                    // level decomposition with constant-W divisions
                    int lb, y, x, rowp;
                    if (pix < 6400)      { int rel = pix;        y = rel / 80; x = rel - y * 80; rowp = 40; lb = 0; }
                    else if (pix < 8000) { int rel = pix - 6400; y = rel / 40; x = rel - y * 40; rowp = 20; lb = 3200; }
                    else if (pix < 8400) { int rel = pix - 8000; y = rel / 20; x = rel - y * 20; rowp = 10; lb = 4000; }
                    else                 { int rel = pix - 8400; y = rel / 10; x = rel - y * 10; rowp = 5;  lb = 4200; }
                    size_t plane = (size_t)(b * NH + h) * PLANE_USH;
                    int yb = lb + y * rowp;
                    // copy 0: even pairs (x0 even)
                    int i0 = (yb + (x >> 1)) * 64 + d * 2 + (x & 1);
                    // copy 1: odd pairs (1,2),(3,4)...,(W-1,0 wrap)
                    int p1 = x ? ((x - 1) >> 1) : (rowp - 1);
                    int s1 = x ? ((x - 1) & 1) : 1;
                    int i1 = (4250 + yb + p1) * 64 + d * 2 + s1;
                    vperm[plane + i0] = cv.u;
                    vperm[plane + i1] = cv.u;
                } else {
                    if (c < 256) off_b[(size_t)row * 256 + c] = f2bf(val + boff[c]);
                    else awl_b[(size_t)row * 128 + (c - 256)] = f2bf(val + battn[c - 256]);
                }
            }
        }
    }
}

// ---------------------------------------------------------------------------
// GEMM3: sampled(bf16) @ Wo + bo -> out fp32
// ---------------------------------------------------------------------------
__global__ __launch_bounds__(256, 3) void gemm_out(
    const ushort_t* __restrict__ A, const ushort_t* __restrict__ BT,
    const float* __restrict__ bo, float* __restrict__ out)
{
    __shared__ ushort_t Asl[128 * 64];
    __shared__ ushort_t Bsl[128 * 64];

    const int m0 = (blockIdx.x >> 1) * 128;    // adjacency swizzle (263x2)
    const int n0 = (blockIdx.x & 1) * 128;
    const int M = 33600;

    f32x4 acc[4][4];
    #pragma unroll
    for (int i = 0; i < 4; i++)
        #pragma unroll
        for (int j = 0; j < 4; j++) acc[i][j] = (f32x4){0.f, 0.f, 0.f, 0.f};

    gemm_core(A, BT, M, m0, n0, Asl, Bsl, acc);

    const int tid  = threadIdx.x;
    const int wave = tid >> 6, lane = tid & 63;
    const int quad = lane >> 4, mr = lane & 15;
    const int wm   = (wave >> 1) * 64, wn = (wave & 1) * 64;

    #pragma unroll
    for (int i = 0; i < 4; i++) {
        const int rbase = m0 + wm + i * 16 + quad * 4;
        #pragma unroll
        for (int j = 0; j < 4; j++) {
            const int c = n0 + wn + j * 16 + mr;
            #pragma unroll
            for (int reg = 0; reg < 4; reg++) {
                int row = rbase + reg;
                if (row >= M) continue;
                out[(size_t)row * 256 + c] = acc[i][j][reg] + bo[c];
            }
        }
    }
}

// ---------------------------------------------------------------------------
// Sampler v10: pair-interleaved gathers. Plane-locality blocks (b, h,
// 32-query chunk), h = bid&7 XCD-pinned, 256 threads, no value staging.
// Phase1: per (q,l,p) thread folds borders into pair weights (wt,wb) and
// two pair byte-offsets (top/bottom row) -> ONE int4 record.
// Phase2: 8 lanes/query; per point: 1 ds_read_b128 + 2 dwordx4 gathers +
// 8 fdot2. No perms, no half-combine shuffles.
// ---------------------------------------------------------------------------
__global__ __launch_bounds__(256) void msda_sample(
    const ushort_t* __restrict__ vperm, const ushort_t* __restrict__ off,
    const ushort_t* __restrict__ awl, const float* __restrict__ refp,
    ushort_t* __restrict__ sampled)
{
    __shared__ int4 s_wi[16 * 33];   // (wt f16x2, wb f16x2, off_top, off_bot)

    const int tid = threadIdx.x;
    const int bid = blockIdx.x;
    const int h   = bid & 7;          // XCD-pinned head
    const int r   = bid >> 3;         // 0..1051
    const int b   = r / 263;
    const int c   = r - b * 263;      // chunk within batch
    const int q0b = c * 32;           // first query (within batch b)
    const size_t bq0 = (size_t)b * LQ + q0b;

    const int Hs[4]    = {80, 40, 20, 10};
    const int pbase[4] = {0, 3200, 4000, 4200};

    #pragma unroll
    for (int it = 0; it < 2; it++) {
        const int s  = it * 256 + tid;
        const int ql = s >> 4, lp = s & 15;
        const int l  = lp >> 2;
        const int qv = (q0b + ql < LQ) ? ql : 0;   // clamp tail chunk reads
        const size_t bq = bq0 + qv;
        const int Wl = Hs[l];

        unsigned od = *(const unsigned*)(off + bq * 256 + h * 32 + lp * 2);
        float ox = bflo(od), oy = bfhi(od);
        float lgt = bflo((unsigned)awl[bq * 128 + h * 16 + lp]);
        // softmax over the 16-lane (q) group, no max pass (bounded logits)
        float e = __expf(lgt);
        float sum = e;
        sum += __shfl_xor(sum, 1, 16);
        sum += __shfl_xor(sum, 2, 16);
        sum += __shfl_xor(sum, 4, 16);
        sum += __shfl_xor(sum, 8, 16);
        float aw = e * __builtin_amdgcn_rcpf(sum);

        float2 rp = *(const float2*)(refp + bq * 8 + l * 2);
        float x = rp.x * (float)Wl + ox - 0.5f;
        float y = rp.y * (float)Wl + oy - 0.5f;
        float x0f = floorf(x), y0f = floorf(y);
        float wx = x - x0f, wy = y - y0f;
        int x0 = (int)x0f, y0 = (int)y0f;
        float hx0 = ((x0 >= 0) & (x0 < Wl)) ? (1.f - wx) : 0.f;
        float hx1 = ((x0 + 1 >= 0) & (x0 + 1 < Wl)) ? wx : 0.f;
        float vy0w = ((y0 >= 0) & (y0 < Wl)) ? (1.f - wy) * aw : 0.f;
        float vy1w = ((y0 + 1 >= 0) & (y0 + 1 < Wl)) ? wy * aw : 0.f;
        // fold borders into a valid adjacent pair (px, px+1)
        int px = min(max(x0, 0), Wl - 2);
        float pl, pr;
        if (x0 < px)      { pl = hx1; pr = 0.f; }   // x0 left of grid
        else if (x0 > px) { pl = 0.f; pr = hx0; }   // x0 == Wl-1
        else              { pl = hx0; pr = hx1; }
        int cy0 = min(max(y0, 0), Wl - 1);
        int cy1 = min(max(y0 + 1, 0), Wl - 1);
        const int copy = px & 1;
        const int p    = copy ? ((px - 1) >> 1) : (px >> 1);
        const int rowp = Wl >> 1;
        const int cb   = copy * 4250 + pbase[l] + p;
        const int otop = (cb + cy0 * rowp) << 7;    // pair byte offsets
        const int obot = (cb + cy1 * rowp) << 7;
        unsigned wt = pk2u(__builtin_amdgcn_cvt_pkrtz(pl * vy0w, pr * vy0w));
        unsigned wb = pk2u(__builtin_amdgcn_cvt_pkrtz(pl * vy1w, pr * vy1w));
        s_wi[lp * 33 + ql] = make_int4((int)wt, (int)wb, otop, obot);
    }
    __syncthreads();

    const int ql  = tid >> 3;          // 0..31
    const int l8  = tid & 7;
    const int dby = l8 * 16;           // byte offset: 4 dims x (L,R) x 2B x ... = 16B

    if (q0b + ql < LQ) {
        const char* plane = (const char*)(vperm + (size_t)(b * NH + h) * PLANE_USH);
        float a0 = 0.f, a1 = 0.f, a2 = 0.f, a3 = 0.f;
        #pragma unroll
        for (int pt = 0; pt < 16; pt++) {
            int4 wi = s_wi[pt * 33 + ql];
            uint4 vt = *(const uint4*)(plane + (unsigned)(wi.z + dby));
            uint4 vb = *(const uint4*)(plane + (unsigned)(wi.w + dby));
            half2_t wt = ash2((unsigned)wi.x);
            half2_t wb = ash2((unsigned)wi.y);
            a0 = __builtin_amdgcn_fdot2(wt, ash2(vt.x), a0, false);
            a0 = __builtin_amdgcn_fdot2(wb, ash2(vb.x), a0, false);
            a1 = __builtin_amdgcn_fdot2(wt, ash2(vt.y), a1, false);
            a1 = __builtin_amdgcn_fdot2(wb, ash2(vb.y), a1, false);
            a2 = __builtin_amdgcn_fdot2(wt, ash2(vt.z), a2, false);
            a2 = __builtin_amdgcn_fdot2(wb, ash2(vb.z), a2, false);
            a3 = __builtin_amdgcn_fdot2(wt, ash2(vt.w), a3, false);
            a3 = __builtin_amdgcn_fdot2(wb, ash2(vb.w), a3, false);
        }
        const size_t bq = bq0 + ql;
        ushort4 o;
        o.x = f2bf(a0); o.y = f2bf(a1);
        o.z = f2bf(a2); o.w = f2bf(a3);
        *(ushort4*)(sampled + bq * 256 + h * 32 + l8 * 4) = o;
    }
}

extern "C" void kernel_launch(void* const* d_in, const int* in_sizes, int n_in,
                              void* d_out, int out_size, void* d_ws, size_t ws_size,
                              hipStream_t stream) {
    const float* query = (const float*)d_in[0];
    const float* refp  = (const float*)d_in[1];
    const float* value = (const float*)d_in[2];
    const float* Wv    = (const float*)d_in[4];
    const float* bv    = (const float*)d_in[5];
    const float* Woff  = (const float*)d_in[6];
    const float* boff  = (const float*)d_in[7];
    const float* Wattn = (const float*)d_in[8];
    const float* battn = (const float*)d_in[9];
    const float* Wo    = (const float*)d_in[10];
    const float* bo    = (const float*)d_in[11];
    float* out = (float*)d_out;

    // Workspace (95.7 MB): off 17.2 + awl 8.6 + value_b 17.4 + query_b 17.2
    //                      + vperm(pair x2) 34.8 + BT 0.46
    ushort_t* ws = (ushort_t*)d_ws;
    ushort_t* off_b   = ws;                       // 33600*256
    ushort_t* awl_b   = off_b + 8601600;          // 33600*128
    ushort_t* value_b = awl_b + 4300800;          // 34000*256
    ushort_t* query_b = value_b + 8704000;        // 33600*256 (aliased w/ sampled)
    ushort_t* vperm_b = query_b + 8601600;        // 32 planes * 544000 (f16 pairs)
    ushort_t* BT      = vperm_b + 17408000;       // 896*256
    ushort_t* sampled_b = query_b;                // alias: query dead after gemm_fused

    prep_all<<<dim3(17796), 256, 0, stream>>>(
        value, query, Wv, Woff, Wattn, Wo, value_b, query_b, BT);

    gemm_fused<<<dim3(532 + 789), 256, 0, stream>>>(
        value_b, query_b, BT, bv, boff, battn, vperm_b, off_b, awl_b);

    msda_sample<<<dim3(8 * 4 * 263), 256, 0, stream>>>(
        vperm_b, off_b, awl_b, refp, sampled_b);

    gemm_out<<<dim3(526), 256, 0, stream>>>(
        sampled_b, BT + 163840, bo, out);
}

// Round 8
// 217.809 us; speedup vs baseline: 1.2373x; 1.0469x over previous
//
#include <hip/hip_runtime.h>
#include <math.h>

#define BB 4
#define LQ 8400
#define NH 8
#define LVTOT 8500
#define HD 32
#define PLANE_USH 544000   // 8500 pairs x 64 ushorts (2 parity copies of 4250)

typedef __attribute__((ext_vector_type(8))) short short8;
typedef __attribute__((ext_vector_type(4))) float f32x4;
typedef __attribute__((ext_vector_type(2))) _Float16 half2_t;
typedef __attribute__((ext_vector_type(2))) __fp16 fp16x2_t;
typedef unsigned short ushort_t;

__device__ __forceinline__ ushort_t f2bf(float f) {
    union { float f; unsigned u; } v; v.f = f;
    unsigned r = v.u + 0x7fffu + ((v.u >> 16) & 1u);   // RNE
    return (ushort_t)(r >> 16);
}
__device__ __forceinline__ float bflo(unsigned u) {
    union { unsigned u; float f; } x; x.u = u << 16; return x.f;
}
__device__ __forceinline__ float bfhi(unsigned u) {
    union { unsigned u; float f; } x; x.u = u & 0xffff0000u; return x.f;
}
__device__ __forceinline__ half2_t ash2(unsigned u) {
    union { unsigned u; half2_t h; } x; x.u = u; return x.h;
}
__device__ __forceinline__ unsigned pk2u(fp16x2_t h) {
    union { fp16x2_t h; unsigned u; } x; x.h = h; return x.u;
}

// async global->LDS DMA, 16 B per lane (wave-uniform LDS base + lane*16)
__device__ __forceinline__ void dma16(const ushort_t* g, ushort_t* l) {
    __builtin_amdgcn_global_load_lds(
        (const __attribute__((address_space(1))) void*)g,
        (__attribute__((address_space(3))) void*)l, 16, 0, 0);
}

// level decomposition of a pixel index (0..8499) -> pair-space geometry
__device__ __forceinline__ void lvl_decomp(int pix, int& lb, int& y, int& x,
                                           int& rowp) {
    if (pix < 6400)      { y = pix / 80;            x = pix - y * 80;  rowp = 40; lb = 0; }
    else if (pix < 8000) { int r = pix - 6400; y = r / 40; x = r - y * 40; rowp = 20; lb = 3200; }
    else if (pix < 8400) { int r = pix - 8000; y = r / 20; x = r - y * 20; rowp = 10; lb = 4000; }
    else                 { int r = pix - 8400; y = r / 10; x = r - y * 10; rowp = 5;  lb = 4200; }
}

// ---------------------------------------------------------------------------
// Merged prep: blocks [0,8500) cast value, [8500,16900) cast query,
// [16900,17796) build BT (transposed bf16 weights, 896 rows x 256 k).
// ---------------------------------------------------------------------------
__global__ __launch_bounds__(256) void prep_all(
    const float* __restrict__ value, const float* __restrict__ query,
    const float* __restrict__ Wv, const float* __restrict__ Woff,
    const float* __restrict__ Wattn, const float* __restrict__ Wo,
    ushort_t* __restrict__ value_b, ushort_t* __restrict__ query_b,
    ushort_t* __restrict__ BT)
{
    const int bid = blockIdx.x;
    if (bid < 16900) {
        const float* src = (bid < 8500) ? value : query;
        ushort_t* dst = (bid < 8500) ? value_b : query_b;
        int i = (bid < 8500 ? bid : bid - 8500) * 256 + threadIdx.x;
        float4 f = ((const float4*)src)[i];
        ushort4 o;
        o.x = f2bf(f.x); o.y = f2bf(f.y); o.z = f2bf(f.z); o.w = f2bf(f.w);
        ((ushort4*)dst)[i] = o;
    } else {
        int idx = (bid - 16900) * 256 + threadIdx.x;   // 896*256
        int r = idx >> 8, k = idx & 255;
        float v;
        if (r < 256) v = Wv[k * 256 + r];
        else if (r < 640) {
            int n = r - 256;
            v = (n < 256) ? Woff[k * 256 + n] : Wattn[k * 128 + (n - 256)];
        } else v = Wo[k * 256 + (r - 640)];
        BT[idx] = f2bf(v);
    }
}

// ---------------------------------------------------------------------------
// Shared GEMM core (serial, proven): 128x128 tile, 4 waves, BK=64.
// Staging via global_load_lds dwordx4; XOR swizzle on the GLOBAL segment.
// ---------------------------------------------------------------------------
__device__ __forceinline__ void gemm_core(
    const ushort_t* __restrict__ A, const ushort_t* __restrict__ B, int M,
    int m0, int n0, ushort_t* Asl, ushort_t* Bsl, f32x4 acc[4][4])
{
    const int tid  = threadIdx.x;
    const int wave = tid >> 6, lane = tid & 63;
    const int quad = lane >> 4, mr = lane & 15;
    const int wm   = (wave >> 1) * 64, wn = (wave & 1) * 64;
    const int oct  = lane >> 3;       // 0..7 row-in-wave-slab
    const int bseg = lane & 7;        // physical 16B slot within row

    for (int k0 = 0; k0 < 256; k0 += 64) {
        __syncthreads();              // prior iteration's reads done
        #pragma unroll
        for (int i = 0; i < 4; i++) {
            int m  = i * 32 + wave * 8 + oct;          // block-relative row
            int gs = bseg ^ (m & 7);                   // swizzled source seg
            int am = min(m0 + m, M - 1);
            dma16(A + (size_t)am * 256 + k0 + gs * 8,
                  Asl + (size_t)(i * 32 + wave * 8) * 64 + lane * 8);
            int bn = n0 + m;
            dma16(B + (size_t)bn * 256 + k0 + gs * 8,
                  Bsl + (size_t)(i * 32 + wave * 8) * 64 + lane * 8);
        }
        __syncthreads();              // DMA landed
        #pragma unroll
        for (int ks = 0; ks < 2; ks++) {
            short8 af[4], bf[4];
            const int ksl = ks * 4 + quad;
            #pragma unroll
            for (int i = 0; i < 4; i++) {
                int m = wm + i * 16 + mr;
                af[i] = *(const short8*)&Asl[m * 64 + (ksl ^ (m & 7)) * 8];
                int n = wn + i * 16 + mr;
                bf[i] = *(const short8*)&Bsl[n * 64 + (ksl ^ (n & 7)) * 8];
            }
            #pragma unroll
            for (int i = 0; i < 4; i++)
                #pragma unroll
                for (int j = 0; j < 4; j++)
                    acc[i][j] = __builtin_amdgcn_mfma_f32_16x16x32_bf16(
                        af[i], bf[j], acc[i][j], 0, 0, 0);
        }
    }
}

// ---------------------------------------------------------------------------
// Fused GEMM1 (value->vperm f16 pair-interleaved x2 parity) + GEMM2
// (query->off/awl). NEW: LDS-repack epilogue — acc is staged into the dead
// Asl/Bsl LDS (XOR-swizzled 128x128 f16 tile), then written with coalesced
// 16B stores: mode1 row-major; mode0 in pair-major units (64 copy0 + 63
// copy1 complete pairs + 2x128 boundary 2B scatters). Wrap pairs (never
// read by the sampler) are skipped.
// ---------------------------------------------------------------------------
__global__ __launch_bounds__(256, 3) void gemm_fused(
    const ushort_t* __restrict__ Av, const ushort_t* __restrict__ Aq,
    const ushort_t* __restrict__ BT,
    const float* __restrict__ bv, const float* __restrict__ boff,
    const float* __restrict__ battn,
    ushort_t* __restrict__ vperm, ushort_t* __restrict__ off_b,
    ushort_t* __restrict__ awl_b)
{
    __shared__ ushort_t smem[16384];   // gemm: Asl|Bsl; epilogue: 128x128 f16
    ushort_t* Asl = smem;
    ushort_t* Bsl = smem + 8192;

    const int bid = blockIdx.x;
    int mode, m0, n0, M;
    const ushort_t *A, *B;
    if (bid < 532) { mode = 0; m0 = (bid >> 1) * 128; n0 = (bid & 1) * 128;
                     A = Av; B = BT; M = 34000; }
    else { int b2 = bid - 532;
           mode = 1; m0 = (b2 / 3) * 128; n0 = (b2 % 3) * 128;
           A = Aq; B = BT + 65536; M = 33600; }

    f32x4 acc[4][4];
    #pragma unroll
    for (int i = 0; i < 4; i++)
        #pragma unroll
        for (int j = 0; j < 4; j++) acc[i][j] = (f32x4){0.f, 0.f, 0.f, 0.f};

    gemm_core(A, B, M, m0, n0, Asl, Bsl, acc);

    const int tid  = threadIdx.x;
    const int wave = tid >> 6, lane = tid & 63;
    const int quad = lane >> 4, mr = lane & 15;
    const int wm   = (wave >> 1) * 64, wn = (wave & 1) * 64;

    // ---- step 1: acc (+bias, cvt) -> swizzled LDS tile ----
    __syncthreads();                   // last K-step's LDS reads done
    #pragma unroll
    for (int i = 0; i < 4; i++) {
        #pragma unroll
        for (int j = 0; j < 4; j++) {
            const int lc = wn + j * 16 + mr;
            const int c  = n0 + lc;
            const float bias = (mode == 0) ? bv[c]
                              : (c < 256 ? boff[c] : battn[c - 256]);
            #pragma unroll
            for (int reg = 0; reg < 4; reg++) {
                const int rl = wm + i * 16 + quad * 4 + reg;
                float val = acc[i][j][reg] + bias;
                ushort_t u;
                if (mode == 0) { union { _Float16 h; ushort_t u; } cv;
                                 cv.h = (_Float16)val; u = cv.u; }
                else u = f2bf(val);
                smem[rl * 128 + (lc ^ ((rl & 3) << 3))] = u;
            }
        }
    }
    __syncthreads();

    // ---- step 2: coalesced stores ----
    if (mode == 1) {
        for (int k = 0; k < 8; k++) {
            int sid = k * 256 + tid;            // 2048 x 16B
            int rl = sid >> 4, cc = (sid & 15) * 8;
            int row = m0 + rl;
            if (row >= M) continue;
            uint4 v = *(const uint4*)&smem[rl * 128 + (cc ^ ((rl & 3) << 3))];
            if (n0 < 256) *(uint4*)&off_b[(size_t)row * 256 + n0 + cc] = v;
            else          *(uint4*)&awl_b[(size_t)row * 128 + cc] = v;
        }
    } else {
        const int hb = n0 >> 5;                 // head base: 0 or 4
        // complete pairs: units 0..63 copy0 (t=2u), 64..126 copy1 (t=2u+1)
        for (int k = 0; k < 16; k++) {
            int sid = k * 256 + tid;            // 4096 slots, 127*32 used
            int unit = sid >> 5;
            if (unit >= 127) continue;
            int sub = sid & 31;
            int hh = sub >> 3, q = sub & 7;
            int copy = (unit >= 64) ? 1 : 0;
            int t = copy ? ((unit - 64) * 2 + 1) : (unit * 2);
            int row = m0 + t;
            if (row + 1 >= 34000) continue;     // need both pixels
            int b = row / LVTOT, pix = row - b * LVTOT;
            int lb, y, x, rowp;
            lvl_decomp(pix, lb, y, x, rowp);
            if (copy && x >= 2 * rowp - 1) continue;   // wrap pair: never read
            int p = x >> 1;                     // (x even: x/2) | (x odd: (x-1)/2)
            int pidx = copy * 4250 + lb + y * rowp + p;
            int h = hb + hh;
            uint2 a  = *(const uint2*)&smem[t * 128 +
                          ((hh * 32 + q * 4) ^ ((t & 3) << 3))];
            uint2 b2 = *(const uint2*)&smem[(t + 1) * 128 +
                          ((hh * 32 + q * 4) ^ (((t + 1) & 3) << 3))];
            uint4 o;
            o.x = (a.x & 0xffffu) | (b2.x << 16);
            o.y = (a.x >> 16)     | (b2.x & 0xffff0000u);
            o.z = (a.y & 0xffffu) | (b2.y << 16);
            o.w = (a.y >> 16)     | (b2.y & 0xffff0000u);
            *(uint4*)((char*)(vperm + (size_t)(b * NH + h) * PLANE_USH)
                      + (size_t)pidx * 128 + q * 16) = o;
        }
        // boundary scatters: pixel t=0 -> slot1 of left pair; t=127 -> slot0
        {
            int pixsel = tid >> 7;              // 0: t=0, 1: t=127
            int rem = tid & 127;
            int hh = rem >> 5, d = rem & 31;
            int t = pixsel ? 127 : 0;
            int row = m0 + t;
            if (row < 34000) {
                int b = row / LVTOT, pix = row - b * LVTOT;
                int lb, y, x, rowp;
                lvl_decomp(pix, lb, y, x, rowp);
                bool doit; int p, slot;
                if (!pixsel) { doit = (x >= 2);            p = (x - 2) >> 1; slot = 1; }
                else         { doit = (x < 2 * rowp - 1);  p = (x - 1) >> 1; slot = 0; }
                if (doit) {
                    int pidx = 4250 + lb + y * rowp + p;
                    int h = hb + hh;
                    vperm[(size_t)(b * NH + h) * PLANE_USH
                          + (size_t)pidx * 64 + d * 2 + slot] =
                        smem[t * 128 + ((hh * 32 + d) ^ ((t & 3) << 3))];
                }
            }
        }
    }
}

// ---------------------------------------------------------------------------
// GEMM3: sampled(bf16) @ Wo + bo -> out fp32 (stores already coalesced)
// ---------------------------------------------------------------------------
__global__ __launch_bounds__(256, 3) void gemm_out(
    const ushort_t* __restrict__ A, const ushort_t* __restrict__ BT,
    const float* __restrict__ bo, float* __restrict__ out)
{
    __shared__ ushort_t Asl[128 * 64];
    __shared__ ushort_t Bsl[128 * 64];

    const int m0 = (blockIdx.x >> 1) * 128;    // adjacency swizzle (263x2)
    const int n0 = (blockIdx.x & 1) * 128;
    const int M = 33600;

    f32x4 acc[4][4];
    #pragma unroll
    for (int i = 0; i < 4; i++)
        #pragma unroll
        for (int j = 0; j < 4; j++) acc[i][j] = (f32x4){0.f, 0.f, 0.f, 0.f};

    gemm_core(A, BT, M, m0, n0, Asl, Bsl, acc);

    const int tid  = threadIdx.x;
    const int wave = tid >> 6, lane = tid & 63;
    const int quad = lane >> 4, mr = lane & 15;
    const int wm   = (wave >> 1) * 64, wn = (wave & 1) * 64;

    #pragma unroll
    for (int i = 0; i < 4; i++) {
        const int rbase = m0 + wm + i * 16 + quad * 4;
        #pragma unroll
        for (int j = 0; j < 4; j++) {
            const int c = n0 + wn + j * 16 + mr;
            #pragma unroll
            for (int reg = 0; reg < 4; reg++) {
                int row = rbase + reg;
                if (row >= M) continue;
                out[(size_t)row * 256 + c] = acc[i][j][reg] + bo[c];
            }
        }
    }
}

// ---------------------------------------------------------------------------
// Sampler v10 (unchanged from round 7): pair-interleaved gathers, plane-
// locality blocks (b, h, 32-query chunk), h = bid&7 XCD-pinned.
// ---------------------------------------------------------------------------
__global__ __launch_bounds__(256) void msda_sample(
    const ushort_t* __restrict__ vperm, const ushort_t* __restrict__ off,
    const ushort_t* __restrict__ awl, const float* __restrict__ refp,
    ushort_t* __restrict__ sampled)
{
    __shared__ int4 s_wi[16 * 33];   // (wt f16x2, wb f16x2, off_top, off_bot)

    const int tid = threadIdx.x;
    const int bid = blockIdx.x;
    const int h   = bid & 7;          // XCD-pinned head
    const int r   = bid >> 3;         // 0..1051
    const int b   = r / 263;
    const int c   = r - b * 263;      // chunk within batch
    const int q0b = c * 32;           // first query (within batch b)
    const size_t bq0 = (size_t)b * LQ + q0b;

    const int Hs[4]    = {80, 40, 20, 10};
    const int pbase[4] = {0, 3200, 4000, 4200};

    #pragma unroll
    for (int it = 0; it < 2; it++) {
        const int s  = it * 256 + tid;
        const int ql = s >> 4, lp = s & 15;
        const int l  = lp >> 2;
        const int qv = (q0b + ql < LQ) ? ql : 0;   // clamp tail chunk reads
        const size_t bq = bq0 + qv;
        const int Wl = Hs[l];

        unsigned od = *(const unsigned*)(off + bq * 256 + h * 32 + lp * 2);
        float ox = bflo(od), oy = bfhi(od);
        float lgt = bflo((unsigned)awl[bq * 128 + h * 16 + lp]);
        // softmax over the 16-lane (q) group, no max pass (bounded logits)
        float e = __expf(lgt);
        float sum = e;
        sum += __shfl_xor(sum, 1, 16);
        sum += __shfl_xor(sum, 2, 16);
        sum += __shfl_xor(sum, 4, 16);
        sum += __shfl_xor(sum, 8, 16);
        float aw = e * __builtin_amdgcn_rcpf(sum);

        float2 rp = *(const float2*)(refp + bq * 8 + l * 2);
        float x = rp.x * (float)Wl + ox - 0.5f;
        float y = rp.y * (float)Wl + oy - 0.5f;
        float x0f = floorf(x), y0f = floorf(y);
        float wx = x - x0f, wy = y - y0f;
        int x0 = (int)x0f, y0 = (int)y0f;
        float hx0 = ((x0 >= 0) & (x0 < Wl)) ? (1.f - wx) : 0.f;
        float hx1 = ((x0 + 1 >= 0) & (x0 + 1 < Wl)) ? wx : 0.f;
        float vy0w = ((y0 >= 0) & (y0 < Wl)) ? (1.f - wy) * aw : 0.f;
        float vy1w = ((y0 + 1 >= 0) & (y0 + 1 < Wl)) ? wy * aw : 0.f;
        // fold borders into a valid adjacent pair (px, px+1)
        int px = min(max(x0, 0), Wl - 2);
        float pl, pr;
        if (x0 < px)      { pl = hx1; pr = 0.f; }   // x0 left of grid
        else if (x0 > px) { pl = 0.f; pr = hx0; }   // x0 == Wl-1
        else              { pl = hx0; pr = hx1; }
        int cy0 = min(max(y0, 0), Wl - 1);
        int cy1 = min(max(y0 + 1, 0), Wl - 1);
        const int copy = px & 1;
        const int p    = copy ? ((px - 1) >> 1) : (px >> 1);
        const int rowp = Wl >> 1;
        const int cb   = copy * 4250 + pbase[l] + p;
        const int otop = (cb + cy0 * rowp) << 7;    // pair byte offsets
        const int obot = (cb + cy1 * rowp) << 7;
        unsigned wt = pk2u(__builtin_amdgcn_cvt_pkrtz(pl * vy0w, pr * vy0w));
        unsigned wb = pk2u(__builtin_amdgcn_cvt_pkrtz(pl * vy1w, pr * vy1w));
        s_wi[lp * 33 + ql] = make_int4((int)wt, (int)wb, otop, obot);
    }
    __syncthreads();

    const int ql  = tid >> 3;          // 0..31
    const int l8  = tid & 7;
    const int dby = l8 * 16;           // byte offset of this lane's 4-dim pair block

    if (q0b + ql < LQ) {
        const char* plane = (const char*)(vperm + (size_t)(b * NH + h) * PLANE_USH);
        float a0 = 0.f, a1 = 0.f, a2 = 0.f, a3 = 0.f;
        #pragma unroll
        for (int pt = 0; pt < 16; pt++) {
            int4 wi = s_wi[pt * 33 + ql];
            uint4 vt = *(const uint4*)(plane + (unsigned)(wi.z + dby));
            uint4 vb = *(const uint4*)(plane + (unsigned)(wi.w + dby));
            half2_t wt = ash2((unsigned)wi.x);
            half2_t wb = ash2((unsigned)wi.y);
            a0 = __builtin_amdgcn_fdot2(wt, ash2(vt.x), a0, false);
            a0 = __builtin_amdgcn_fdot2(wb, ash2(vb.x), a0, false);
            a1 = __builtin_amdgcn_fdot2(wt, ash2(vt.y), a1, false);
            a1 = __builtin_amdgcn_fdot2(wb, ash2(vb.y), a1, false);
            a2 = __builtin_amdgcn_fdot2(wt, ash2(vt.z), a2, false);
            a2 = __builtin_amdgcn_fdot2(wb, ash2(vb.z), a2, false);
            a3 = __builtin_amdgcn_fdot2(wt, ash2(vt.w), a3, false);
            a3 = __builtin_amdgcn_fdot2(wb, ash2(vb.w), a3, false);
        }
        const size_t bq = bq0 + ql;
        ushort4 o;
        o.x = f2bf(a0); o.y = f2bf(a1);
        o.z = f2bf(a2); o.w = f2bf(a3);
        *(ushort4*)(sampled + bq * 256 + h * 32 + l8 * 4) = o;
    }
}

extern "C" void kernel_launch(void* const* d_in, const int* in_sizes, int n_in,
                              void* d_out, int out_size, void* d_ws, size_t ws_size,
                              hipStream_t stream) {
    const float* query = (const float*)d_in[0];
    const float* refp  = (const float*)d_in[1];
    const float* value = (const float*)d_in[2];
    const float* Wv    = (const float*)d_in[4];
    const float* bv    = (const float*)d_in[5];
    const float* Woff  = (const float*)d_in[6];
    const float* boff  = (const float*)d_in[7];
    const float* Wattn = (const float*)d_in[8];
    const float* battn = (const float*)d_in[9];
    const float* Wo    = (const float*)d_in[10];
    const float* bo    = (const float*)d_in[11];
    float* out = (float*)d_out;

    // Workspace (95.7 MB): off 17.2 + awl 8.6 + value_b 17.4 + query_b 17.2
    //                      + vperm(pair x2) 34.8 + BT 0.46
    ushort_t* ws = (ushort_t*)d_ws;
    ushort_t* off_b   = ws;                       // 33600*256
    ushort_t* awl_b   = off_b + 8601600;          // 33600*128
    ushort_t* value_b = awl_b + 4300800;          // 34000*256
    ushort_t* query_b = value_b + 8704000;        // 33600*256 (aliased w/ sampled)
    ushort_t* vperm_b = query_b + 8601600;        // 32 planes * 544000 (f16 pairs)
    ushort_t* BT      = vperm_b + 17408000;       // 896*256
    ushort_t* sampled_b = query_b;                // alias: query dead after gemm_fused

    prep_all<<<dim3(17796), 256, 0, stream>>>(
        value, query, Wv, Woff, Wattn, Wo, value_b, query_b, BT);

    gemm_fused<<<dim3(532 + 789), 256, 0, stream>>>(
        value_b, query_b, BT, bv, boff, battn, vperm_b, off_b, awl_b);

    msda_sample<<<dim3(8 * 4 * 263), 256, 0, stream>>>(
        vperm_b, off_b, awl_b, refp, sampled_b);

    gemm_out<<<dim3(526), 256, 0, stream>>>(
        sampled_b, BT + 163840, bo, out);
}